// Round 4
// baseline (1014.169 us; speedup 1.0000x reference)
//
#include <hip/hip_runtime.h>

#define S_LEN 3072
#define NHQ 16
#define NKVH 8
#define HDIM 256
#define WIN 2048
#define QKV_COLS 8192

typedef __bf16 bf16x8 __attribute__((ext_vector_type(8)));
typedef float f32x4 __attribute__((ext_vector_type(4)));
typedef float f32x16 __attribute__((ext_vector_type(16)));

__device__ __forceinline__ unsigned short f2bf(float f) {
    union { float f; unsigned u; } v; v.f = f;
    unsigned r = v.u + 0x7FFFu + ((v.u >> 16) & 1u);
    return (unsigned short)(r >> 16);
}
__device__ __forceinline__ float bf2f(unsigned short u) {
    union { unsigned u; float f; } v; v.u = ((unsigned)u) << 16; return v.f;
}

typedef __attribute__((address_space(3))) void lds_void_t;
typedef const __attribute__((address_space(1))) void glb_void_t;
__device__ __forceinline__ void async16(const void* g, void* l) {
    __builtin_amdgcn_global_load_lds((glb_void_t*)g, (lds_void_t*)l, 16, 0, 0);
}

// ---------------- fp32 -> bf16 cast ----------------
__global__ __launch_bounds__(256) void cast_bf16_kernel(const float* __restrict__ src,
                                                        unsigned short* __restrict__ dst,
                                                        int n) {
    int i = (blockIdx.x * 256 + threadIdx.x) * 4;
    if (i >= n) return;
    float4 v = *(const float4*)(src + i);
    ushort4 o;
    o.x = f2bf(v.x); o.y = f2bf(v.y); o.z = f2bf(v.z); o.w = f2bf(v.w);
    *(ushort4*)(dst + i) = o;
}

// ---------------- bf16 GEMM: C[M,N] = A[M,K] @ B[N,K]^T ----------------
// XCD-aware bijective block swizzle (T1): each XCD gets a contiguous run of
// linear block ids -> A-panel stays L2-resident per XCD while bn sweeps.
// Requires nwg % 8 == 0 (true for both launches: 1536, 672); else fallback.
template <int OUT_BF16>
__global__ __launch_bounds__(256) void gemm_bt(const unsigned short* __restrict__ A,
                                               const unsigned short* __restrict__ B,
                                               void* __restrict__ Cv,
                                               int N, int K) {
    __shared__ __align__(16) unsigned short At[128 * 32];
    __shared__ __align__(16) unsigned short Bt[128 * 32];
    const int tid = threadIdx.x;
    const int wid = tid >> 6, lane = tid & 63;
    const int ln = lane & 15, quad = lane >> 4;

    int bm, bn;
    {
        const int nwg = gridDim.x * gridDim.y;
        int orig = blockIdx.y * gridDim.x + blockIdx.x;
        int wg = orig;
        if ((nwg & 7) == 0) {
            const int cpx = nwg >> 3;
            wg = (orig & 7) * cpx + (orig >> 3);
        }
        bm = wg / gridDim.x;
        bn = wg % gridDim.x;
    }
    const int wm = wid >> 1, wn = wid & 1;

    const f32x4 fzero = {0.f, 0.f, 0.f, 0.f};
    f32x4 acc[4][4];
#pragma unroll
    for (int i = 0; i < 4; i++) {
#pragma unroll
        for (int j = 0; j < 4; j++) acc[i][j] = fzero;
    }

    const unsigned short* gA = A + (size_t)(bm * 128 + wid * 32 + (lane >> 2)) * K + (lane & 3) * 8;
    const unsigned short* gB = B + (size_t)(bn * 128 + wid * 32 + (lane >> 2)) * K + (lane & 3) * 8;
    unsigned short* lA = At + wid * 32 * 32;
    unsigned short* lB = Bt + wid * 32 * 32;

    for (int k0 = 0; k0 < K; k0 += 32) {
        async16(gA + k0, lA);
        async16(gA + k0 + 16 * K, lA + 16 * 32);
        async16(gB + k0, lB);
        async16(gB + k0 + 16 * K, lB + 16 * 32);
        __syncthreads();

        bf16x8 af[4], bfr[4];
#pragma unroll
        for (int mt = 0; mt < 4; mt++)
            af[mt] = *(const bf16x8*)(At + (wm * 64 + mt * 16 + ln) * 32 + quad * 8);
#pragma unroll
        for (int nt = 0; nt < 4; nt++)
            bfr[nt] = *(const bf16x8*)(Bt + (wn * 64 + nt * 16 + ln) * 32 + quad * 8);
#pragma unroll
        for (int mt = 0; mt < 4; mt++) {
#pragma unroll
            for (int nt = 0; nt < 4; nt++)
                acc[mt][nt] = __builtin_amdgcn_mfma_f32_16x16x32_bf16(af[mt], bfr[nt], acc[mt][nt], 0, 0, 0);
        }
        __syncthreads();
    }

    const int row0 = bm * 128 + wm * 64 + quad * 4;
    const int col0 = bn * 128 + wn * 64 + ln;
    if (OUT_BF16) {
        unsigned short* C = (unsigned short*)Cv;
#pragma unroll
        for (int mt = 0; mt < 4; mt++) {
#pragma unroll
            for (int nt = 0; nt < 4; nt++) {
#pragma unroll
                for (int rr = 0; rr < 4; rr++)
                    C[(size_t)(row0 + mt * 16 + rr) * N + col0 + nt * 16] = f2bf(acc[mt][nt][rr]);
            }
        }
    } else {
        float* C = (float*)Cv;
#pragma unroll
        for (int mt = 0; mt < 4; mt++) {
#pragma unroll
            for (int nt = 0; nt < 4; nt++) {
#pragma unroll
                for (int rr = 0; rr < 4; rr++)
                    C[(size_t)(row0 + mt * 16 + rr) * N + col0 + nt * 16] = acc[mt][nt][rr];
            }
        }
    }
}

// ---------------- RoPE for Q (scaled) and K ----------------
__global__ __launch_bounds__(256) void rope_kernel(const unsigned short* __restrict__ qkv,
                                                   const float* __restrict__ freqs,
                                                   const int* __restrict__ kvidx,
                                                   unsigned short* __restrict__ Qb,
                                                   unsigned short* __restrict__ Kb) {
    int t = blockIdx.x * 256 + threadIdx.x;
    int d = t & 127;
    int t2 = t >> 7;
    int hh = t2 % 24;
    int pos = t2 / 24;
    if (pos >= S_LEN) return;
    float2 cs = *(const float2*)(freqs + ((size_t)pos * 128 + d) * 2);
    if (hh < NHQ) {
        const unsigned short* src = qkv + (size_t)pos * QKV_COLS + hh * HDIM + d;
        float x1 = bf2f(src[0]), x2 = bf2f(src[128]);
        float o1 = (x1 * cs.x - x2 * cs.y) * 0.0625f;
        float o2 = (x1 * cs.y + x2 * cs.x) * 0.0625f;
        unsigned short* dst = Qb + ((size_t)hh * S_LEN + pos) * HDIM + d;
        dst[0] = f2bf(o1);
        dst[128] = f2bf(o2);
    } else {
        int kvh = hh - NHQ;
        const unsigned short* src = qkv + (size_t)pos * QKV_COLS + NHQ * HDIM + kvh * HDIM + d;
        float x1 = bf2f(src[0]), x2 = bf2f(src[128]);
        float o1 = x1 * cs.x - x2 * cs.y;
        float o2 = x1 * cs.y + x2 * cs.x;
        int wpos = kvidx[pos];
        unsigned short* dst = Kb + ((size_t)kvh * S_LEN + wpos) * HDIM + d;
        dst[0] = f2bf(o1);
        dst[128] = f2bf(o2);
    }
}

// ---------------- V transpose ----------------
__global__ __launch_bounds__(256) void vtrans_kernel(const unsigned short* __restrict__ qkv,
                                                     const int* __restrict__ kvidx,
                                                     unsigned short* __restrict__ Vbt) {
    __shared__ unsigned short T[64][72];
    int pos0 = blockIdx.x * 64;
    int c0 = blockIdx.y * 64;
    int a = threadIdx.x >> 6;
    int b = threadIdx.x & 63;
#pragma unroll
    for (int r = 0; r < 16; r++) {
        int pl = r * 4 + a;
        T[pl][b] = qkv[(size_t)(pos0 + pl) * QKV_COLS + 6144 + c0 + b];
    }
    __syncthreads();
    int wpos = kvidx[pos0 + b];
#pragma unroll
    for (int r = 0; r < 16; r++) {
        int cl = r * 4 + a;
        Vbt[(size_t)(c0 + cl) * S_LEN + wpos] = T[b][cl];
    }
}

// ---------------- flash attention v6: 32x32 MFMA, 4-wave blocks ----------------
// 1280 blocks of 256 threads: (head, chunk-unit over 128-row q-blocks).
// 4 waves, each owning 32 q-rows of ONE head via 32x32x16 MFMA -> LDS bytes
// per q-row halved vs the 16x16 v4. vs the failed v5 (8-wave/512-thread):
// a 4-wave block may run at 1 wave/SIMD, so __launch_bounds__(256,1) truly
// lifts the 256-VGPR cap (the regime both v5 failures shared).
// Swapped C layout (lane=key, regs=16 q-rows: q=(r&3)+8*(r>>2)+4*(lane>>5));
// P relayout via 2KB wave-private XOR-swizzled LDS; K/V DMA double-buffer with
// one raw s_barrier + vmcnt(0) per tile (verified v4 pipeline).
__global__ __launch_bounds__(256, 1) void attn_kernel(const unsigned short* __restrict__ Qb,
                                                      const unsigned short* __restrict__ Kb,
                                                      const unsigned short* __restrict__ Vbt,
                                                      float* __restrict__ Acc,
                                                      float* __restrict__ Ps,
                                                      unsigned short* __restrict__ attn_out) {
    __shared__ __align__(16) unsigned short Kl[2][32 * 256];   // 2 x 16 KB, keys x dims (chunk-swizzled)
    __shared__ __align__(16) unsigned short Vl[2][256 * 32];   // 2 x 16 KB, dims x keys (chunk-swizzled)
    __shared__ __align__(16) unsigned short Plb[4][1024];      // per-wave P [32 q][32 k], swizzled

    // decode (h, it): per head, 24 q-blocks of 128 rows, balanced chunks
    const int h = blockIdx.x / 80;
    const int it = 79 - (blockIdx.x % 80);
    int qb, sub, nc;
    if (it < 4)       { qb = it; sub = 0; nc = 1; }
    else if (it < 12) { int e = it - 4;  qb = 4 + (e >> 1); sub = e & 1;  nc = 2; }
    else if (it < 24) { int e = it - 12; qb = 8 + e / 3;    sub = e % 3;  nc = 3; }
    else if (it < 40) { int e = it - 24; qb = 12 + (e >> 2); sub = e & 3; nc = 4; }
    else              { int e = it - 40; qb = 16 + e / 5;   sub = e % 5;  nc = 5; }

    const int kv = h >> 1;
    const int q0 = qb * 128;
    const int tid = threadIdx.x;
    const int wid = tid >> 6, lane = tid & 63;
    const int ln32 = lane & 31, hi = lane >> 5;
    const int qw0 = q0 + wid * 32;              // this wave's 32 q-rows

    // Q fragments: A-operand row = lane&31, k = (lane>>5)*8 + j per 16-chunk
    bf16x8 qf[16];
    {
        const unsigned short* qrow = Qb + ((size_t)h * S_LEN + qw0 + ln32) * HDIM + hi * 8;
#pragma unroll
        for (int s = 0; s < 16; s++)
            qf[s] = *(const bf16x8*)(qrow + s * 16);
    }

    f32x16 pacc[8];
#pragma unroll
    for (int dt = 0; dt < 8; dt++) {
#pragma unroll
        for (int i = 0; i < 16; i++) pacc[dt][i] = 0.f;
    }
    float ps[16];
#pragma unroll
    for (int r = 0; r < 16; r++) ps[r] = 0.f;

    const int imin = qw0;
    const int imax = qw0 + 31;

    const int t_lo = (q0 >= WIN) ? ((q0 - (WIN - 1)) >> 5) : 0;
    const int t_hi = (q0 + 127) >> 5;
    const int tn = t_hi - t_lo + 1;
    const int ts = t_lo + (tn * sub) / nc;
    const int te = t_lo + (tn * (sub + 1)) / nc;

    // ---- DMA staging source pointers (pre-swizzled; same scheme as v4/v5) ----
    // K tile = 1024 16B-chunks; call c stages chunks c*256+tid:
    //   row = c*8 + (tid>>5), pos = tid&31, content = K[row][pos ^ (row&7)]
    //   (row&7 = (tid>>5)&7 since c*8 = 0 mod 8 -> swizzle term call-invariant)
    const unsigned short* kSrcA = Kb + ((size_t)kv * S_LEN + (tid >> 5)) * HDIM
                                  + ((tid & 31) ^ ((tid >> 5) & 7)) * 8;
    // V tile: call c stages chunks c*256+tid:
    //   row = c*64 + (tid>>2), pos = tid&3, content = V^T[row][pos ^ ((row>>1)&3)]
    //   ((row>>1)&3 = (tid>>3)&3 since c*64 = 0 mod 8)
    const unsigned short* vSrcA = Vbt + ((size_t)kv * HDIM + (tid >> 2)) * S_LEN
                                  + ((tid & 3) ^ ((tid >> 3) & 3)) * 8;

    // prologue: stage first tile into buffer 0
    {
        const int p0s = ts * 32;
        const unsigned short* ksg = kSrcA + (size_t)p0s * HDIM;
        const unsigned short* vsg = vSrcA + p0s;
#pragma unroll
        for (int c = 0; c < 4; c++)
            async16(ksg + (size_t)(c * 8) * HDIM, &Kl[0][(c * 256 + tid) * 8]);
#pragma unroll
        for (int c = 0; c < 4; c++)
            async16(vsg + (size_t)(c * 64) * S_LEN, &Vl[0][(c * 256 + tid) * 8]);
    }

    unsigned short* plw = &Plb[wid][0];
    const int kswz = ln32 & 7;
    int cur = 0;

    for (int tt = ts; tt < te; tt++) {
        asm volatile("s_waitcnt vmcnt(0)" ::: "memory");
        __builtin_amdgcn_s_barrier();
        asm volatile("" ::: "memory");

        if (tt + 1 < te) {
            const int p0n = (tt + 1) * 32;
            const unsigned short* ksg = kSrcA + (size_t)p0n * HDIM;
            const unsigned short* vsg = vSrcA + p0n;
#pragma unroll
            for (int c = 0; c < 4; c++)
                async16(ksg + (size_t)(c * 8) * HDIM, &Kl[cur ^ 1][(c * 256 + tid) * 8]);
#pragma unroll
            for (int c = 0; c < 4; c++)
                async16(vsg + (size_t)(c * 64) * S_LEN, &Vl[cur ^ 1][(c * 256 + tid) * 8]);
        }

        const int p0 = tt * 32;
        const bool live = (p0 <= imax) && (p0 + 31 >= imin - WIN + 1);
        if (live) {
            // QK^T: S[32q][32k]; A=Q (regs), B=K from LDS.
            // B-frag: key=lane&31, dims (s*16+hi*8..+7); chunk = (s*2+hi)^kswz
            const unsigned short* kb = Kl[cur];
            f32x16 sacc;
#pragma unroll
            for (int i = 0; i < 16; i++) sacc[i] = 0.f;
#pragma unroll
            for (int s = 0; s < 16; s++) {
                bf16x8 kf = *(const bf16x8*)(kb + ln32 * 256 + ((((s << 1) + hi) ^ kswz) << 3));
                sacc = __builtin_amdgcn_mfma_f32_32x32x16_bf16(qf[s], kf, sacc, 0, 0, 0);
            }

            const bool full = (p0 + 31 <= imin) && (p0 >= imax - WIN + 1);
#pragma unroll
            for (int r = 0; r < 16; r++) {
                float z = __expf(sacc[r] * 0.04f);
                float t = fmaf(-100.f, __builtin_amdgcn_rcpf(z + 1.f), 50.f);
                float p = __expf(t);
                const int qloc = (r & 3) + 8 * (r >> 2) + 4 * hi;
                if (!full) {
                    const int i = qw0 + qloc;
                    const int j = p0 + ln32;
                    p = ((j <= i) && (j + WIN > i)) ? p : 0.f;
                }
                ps[r] += p;
                plw[qloc * 32 + (((ln32 >> 3) ^ ((qloc >> 1) & 3)) << 3) + (ln32 & 7)] = f2bf(p);
            }

            // PV: out[32q][256d]; A=P (row=q=lane&31, k=keys), B=V [d][key]
            bf16x8 pa0 = *(const bf16x8*)(plw + ln32 * 32 + ((hi ^ ((ln32 >> 1) & 3)) << 3));
            bf16x8 pa1 = *(const bf16x8*)(plw + ln32 * 32 + (((2 + hi) ^ ((ln32 >> 1) & 3)) << 3));
            const unsigned short* vb = Vl[cur];
#pragma unroll
            for (int dt = 0; dt < 8; dt++) {
                const int d = dt * 32 + ln32;
                const int vswz = (d >> 1) & 3;
                bf16x8 v0 = *(const bf16x8*)(vb + d * 32 + ((hi ^ vswz) << 3));
                pacc[dt] = __builtin_amdgcn_mfma_f32_32x32x16_bf16(pa0, v0, pacc[dt], 0, 0, 0);
                bf16x8 v1 = *(const bf16x8*)(vb + d * 32 + (((2 + hi) ^ vswz) << 3));
                pacc[dt] = __builtin_amdgcn_mfma_f32_32x32x16_bf16(pa1, v1, pacc[dt], 0, 0, 0);
            }
        }
        cur ^= 1;
    }

    // reduce ps over the 32 lanes of each half-wave (keys axis)
#pragma unroll
    for (int r = 0; r < 16; r++) {
        float s = ps[r];
#pragma unroll
        for (int o = 1; o <= 16; o <<= 1)
            s += __shfl_xor(s, o);
        ps[r] = s;
    }

    if (nc == 1) {
#pragma unroll
        for (int dt = 0; dt < 8; dt++) {
#pragma unroll
            for (int r = 0; r < 16; r++) {
                const int q = qw0 + (r & 3) + 8 * (r >> 2) + 4 * hi;
                float o = pacc[dt][r] * __builtin_amdgcn_rcpf(ps[r]);
                attn_out[(size_t)q * 4096 + h * HDIM + dt * 32 + ln32] = f2bf(o);
            }
        }
    } else {
        if (ln32 == 0) {
#pragma unroll
            for (int r = 0; r < 16; r++) {
                const int q = qw0 + (r & 3) + 8 * (r >> 2) + 4 * hi;
                atomicAdd(&Ps[h * S_LEN + q], ps[r]);
            }
        }
#pragma unroll
        for (int dt = 0; dt < 8; dt++) {
#pragma unroll
            for (int r = 0; r < 16; r++) {
                const int q = qw0 + (r & 3) + 8 * (r >> 2) + 4 * hi;
                atomicAdd(&Acc[((size_t)h * S_LEN + q) * HDIM + dt * 32 + ln32], pacc[dt][r]);
            }
        }
    }
}

// ---------------- normalize chunked rows (pos >= 512) ----------------
__global__ __launch_bounds__(256) void norm_kernel(const float* __restrict__ Acc,
                                                   const float* __restrict__ Ps,
                                                   unsigned short* __restrict__ attn_out) {
    int row = blockIdx.x * 4 + (threadIdx.x >> 6);   // over 16*2560 rows
    int lane = threadIdx.x & 63;
    int h = row / 2560;
    int pos = 512 + (row - h * 2560);
    float4 a = *(const float4*)(Acc + ((size_t)h * S_LEN + pos) * HDIM + lane * 4);
    float inv = __builtin_amdgcn_rcpf(Ps[h * S_LEN + pos]);
    ushort4 o;
    o.x = f2bf(a.x * inv); o.y = f2bf(a.y * inv);
    o.z = f2bf(a.z * inv); o.w = f2bf(a.w * inv);
    *(ushort4*)(attn_out + (size_t)pos * 4096 + h * HDIM + lane * 4) = o;
}

// ---------------- launch ----------------
extern "C" void kernel_launch(void* const* d_in, const int* in_sizes, int n_in,
                              void* d_out, int out_size, void* d_ws, size_t ws_size,
                              hipStream_t stream) {
    (void)in_sizes; (void)n_in; (void)out_size; (void)ws_size;
    const float* hidden = (const float*)d_in[0];
    const float* freqs  = (const float*)d_in[1];
    const int* kvidx    = (const int*)d_in[2];
    const float* qkv_w  = (const float*)d_in[6];
    const float* o_w    = (const float*)d_in[7];
    float* out = (float*)d_out;

    char* ws = (char*)d_ws;
    unsigned short* hs_bf   = (unsigned short*)(ws);                 // 22.0 MB (gemm1 input; Ps reuses after)
    unsigned short* w1_bf   = (unsigned short*)(ws + 22020096);
    unsigned short* w2_bf   = (unsigned short*)(ws + 80740352);
    unsigned short* qkv_bf  = (unsigned short*)(ws + 110100480);     // 50.3 MB (Acc reuses after rope/vtrans)
    unsigned short* Qb      = (unsigned short*)(ws + 160432128);
    unsigned short* Kb      = (unsigned short*)(ws + 185597952);
    unsigned short* Vbt     = (unsigned short*)(ws + 198180864);
    unsigned short* attn_bf = (unsigned short*)(ws + 210763776);

    float* Acc = (float*)(ws + 110100480);   // 16*3072*256*4 = 50,331,648 B exactly
    float* Ps  = (float*)(ws);               // 16*3072*4 = 196,608 B (over retired hs_bf)

    cast_bf16_kernel<<<10752, 256, 0, stream>>>(hidden, hs_bf, 11010048);
    cast_bf16_kernel<<<28672, 256, 0, stream>>>(qkv_w, w1_bf, 29360128);
    cast_bf16_kernel<<<14336, 256, 0, stream>>>(o_w, w2_bf, 14680064);

    gemm_bt<1><<<dim3(64, 24), 256, 0, stream>>>(hs_bf, w1_bf, (void*)qkv_bf, 8192, 3584);

    rope_kernel<<<36864, 256, 0, stream>>>(qkv_bf, freqs, kvidx, Qb, Kb);
    vtrans_kernel<<<dim3(48, 32), 256, 0, stream>>>(qkv_bf, kvidx, Vbt);

    // zero partial buffers (regions retired by gemm1/rope/vtrans above)
    hipMemsetAsync(Acc, 0, (size_t)16 * 3072 * 256 * 4, stream);
    hipMemsetAsync(Ps, 0, (size_t)16 * 3072 * 4, stream);

    attn_kernel<<<1280, 256, 0, stream>>>(Qb, Kb, Vbt, Acc, Ps, attn_bf);
    norm_kernel<<<10240, 256, 0, stream>>>(Acc, Ps, attn_bf);

    gemm_bt<0><<<dim3(28, 24), 256, 0, stream>>>(attn_bf, w2_bf, (void*)out, 3584, 4096);
}

// Round 5
// 904.274 us; speedup vs baseline: 1.1215x; 1.1215x over previous
//
#include <hip/hip_runtime.h>

#define S_LEN 3072
#define NHQ 16
#define NKVH 8
#define HDIM 256
#define WIN 2048
#define QKV_COLS 8192

typedef __bf16 bf16x8 __attribute__((ext_vector_type(8)));
typedef float f32x4 __attribute__((ext_vector_type(4)));
typedef float f32x16 __attribute__((ext_vector_type(16)));

__device__ __forceinline__ unsigned short f2bf(float f) {
    union { float f; unsigned u; } v; v.f = f;
    unsigned r = v.u + 0x7FFFu + ((v.u >> 16) & 1u);
    return (unsigned short)(r >> 16);
}
__device__ __forceinline__ float bf2f(unsigned short u) {
    union { unsigned u; float f; } v; v.u = ((unsigned)u) << 16; return v.f;
}

typedef __attribute__((address_space(3))) void lds_void_t;
typedef const __attribute__((address_space(1))) void glb_void_t;
__device__ __forceinline__ void async16(const void* g, void* l) {
    __builtin_amdgcn_global_load_lds((glb_void_t*)g, (lds_void_t*)l, 16, 0, 0);
}

// ---------------- fp32 -> bf16 cast ----------------
__global__ __launch_bounds__(256) void cast_bf16_kernel(const float* __restrict__ src,
                                                        unsigned short* __restrict__ dst,
                                                        int n) {
    int i = (blockIdx.x * 256 + threadIdx.x) * 4;
    if (i >= n) return;
    float4 v = *(const float4*)(src + i);
    ushort4 o;
    o.x = f2bf(v.x); o.y = f2bf(v.y); o.z = f2bf(v.z); o.w = f2bf(v.w);
    *(ushort4*)(dst + i) = o;
}

// ---------------- bf16 GEMM: C[M,N] = A[M,K] @ B[N,K]^T ----------------
// XCD-aware bijective block swizzle (T1): each XCD gets a contiguous run of
// linear block ids -> A-panel stays L2-resident per XCD while bn sweeps.
template <int OUT_BF16>
__global__ __launch_bounds__(256) void gemm_bt(const unsigned short* __restrict__ A,
                                               const unsigned short* __restrict__ B,
                                               void* __restrict__ Cv,
                                               int N, int K) {
    __shared__ __align__(16) unsigned short At[128 * 32];
    __shared__ __align__(16) unsigned short Bt[128 * 32];
    const int tid = threadIdx.x;
    const int wid = tid >> 6, lane = tid & 63;
    const int ln = lane & 15, quad = lane >> 4;

    int bm, bn;
    {
        const int nwg = gridDim.x * gridDim.y;
        int orig = blockIdx.y * gridDim.x + blockIdx.x;
        int wg = orig;
        if ((nwg & 7) == 0) {
            const int cpx = nwg >> 3;
            wg = (orig & 7) * cpx + (orig >> 3);
        }
        bm = wg / gridDim.x;
        bn = wg % gridDim.x;
    }
    const int wm = wid >> 1, wn = wid & 1;

    const f32x4 fzero = {0.f, 0.f, 0.f, 0.f};
    f32x4 acc[4][4];
#pragma unroll
    for (int i = 0; i < 4; i++) {
#pragma unroll
        for (int j = 0; j < 4; j++) acc[i][j] = fzero;
    }

    const unsigned short* gA = A + (size_t)(bm * 128 + wid * 32 + (lane >> 2)) * K + (lane & 3) * 8;
    const unsigned short* gB = B + (size_t)(bn * 128 + wid * 32 + (lane >> 2)) * K + (lane & 3) * 8;
    unsigned short* lA = At + wid * 32 * 32;
    unsigned short* lB = Bt + wid * 32 * 32;

    for (int k0 = 0; k0 < K; k0 += 32) {
        async16(gA + k0, lA);
        async16(gA + k0 + 16 * K, lA + 16 * 32);
        async16(gB + k0, lB);
        async16(gB + k0 + 16 * K, lB + 16 * 32);
        __syncthreads();

        bf16x8 af[4], bfr[4];
#pragma unroll
        for (int mt = 0; mt < 4; mt++)
            af[mt] = *(const bf16x8*)(At + (wm * 64 + mt * 16 + ln) * 32 + quad * 8);
#pragma unroll
        for (int nt = 0; nt < 4; nt++)
            bfr[nt] = *(const bf16x8*)(Bt + (wn * 64 + nt * 16 + ln) * 32 + quad * 8);
#pragma unroll
        for (int mt = 0; mt < 4; mt++) {
#pragma unroll
            for (int nt = 0; nt < 4; nt++)
                acc[mt][nt] = __builtin_amdgcn_mfma_f32_16x16x32_bf16(af[mt], bfr[nt], acc[mt][nt], 0, 0, 0);
        }
        __syncthreads();
    }

    const int row0 = bm * 128 + wm * 64 + quad * 4;
    const int col0 = bn * 128 + wn * 64 + ln;
    if (OUT_BF16) {
        unsigned short* C = (unsigned short*)Cv;
#pragma unroll
        for (int mt = 0; mt < 4; mt++) {
#pragma unroll
            for (int nt = 0; nt < 4; nt++) {
#pragma unroll
                for (int rr = 0; rr < 4; rr++)
                    C[(size_t)(row0 + mt * 16 + rr) * N + col0 + nt * 16] = f2bf(acc[mt][nt][rr]);
            }
        }
    } else {
        float* C = (float*)Cv;
#pragma unroll
        for (int mt = 0; mt < 4; mt++) {
#pragma unroll
            for (int nt = 0; nt < 4; nt++) {
#pragma unroll
                for (int rr = 0; rr < 4; rr++)
                    C[(size_t)(row0 + mt * 16 + rr) * N + col0 + nt * 16] = acc[mt][nt][rr];
            }
        }
    }
}

// ---------------- RoPE for Q (scaled) and K ----------------
__global__ __launch_bounds__(256) void rope_kernel(const unsigned short* __restrict__ qkv,
                                                   const float* __restrict__ freqs,
                                                   const int* __restrict__ kvidx,
                                                   unsigned short* __restrict__ Qb,
                                                   unsigned short* __restrict__ Kb) {
    int t = blockIdx.x * 256 + threadIdx.x;
    int d = t & 127;
    int t2 = t >> 7;
    int hh = t2 % 24;
    int pos = t2 / 24;
    if (pos >= S_LEN) return;
    float2 cs = *(const float2*)(freqs + ((size_t)pos * 128 + d) * 2);
    if (hh < NHQ) {
        const unsigned short* src = qkv + (size_t)pos * QKV_COLS + hh * HDIM + d;
        float x1 = bf2f(src[0]), x2 = bf2f(src[128]);
        float o1 = (x1 * cs.x - x2 * cs.y) * 0.0625f;
        float o2 = (x1 * cs.y + x2 * cs.x) * 0.0625f;
        unsigned short* dst = Qb + ((size_t)hh * S_LEN + pos) * HDIM + d;
        dst[0] = f2bf(o1);
        dst[128] = f2bf(o2);
    } else {
        int kvh = hh - NHQ;
        const unsigned short* src = qkv + (size_t)pos * QKV_COLS + NHQ * HDIM + kvh * HDIM + d;
        float x1 = bf2f(src[0]), x2 = bf2f(src[128]);
        float o1 = x1 * cs.x - x2 * cs.y;
        float o2 = x1 * cs.y + x2 * cs.x;
        int wpos = kvidx[pos];
        unsigned short* dst = Kb + ((size_t)kvh * S_LEN + wpos) * HDIM + d;
        dst[0] = f2bf(o1);
        dst[128] = f2bf(o2);
    }
}

// ---------------- V transpose ----------------
__global__ __launch_bounds__(256) void vtrans_kernel(const unsigned short* __restrict__ qkv,
                                                     const int* __restrict__ kvidx,
                                                     unsigned short* __restrict__ Vbt) {
    __shared__ unsigned short T[64][72];
    int pos0 = blockIdx.x * 64;
    int c0 = blockIdx.y * 64;
    int a = threadIdx.x >> 6;
    int b = threadIdx.x & 63;
#pragma unroll
    for (int r = 0; r < 16; r++) {
        int pl = r * 4 + a;
        T[pl][b] = qkv[(size_t)(pos0 + pl) * QKV_COLS + 6144 + c0 + b];
    }
    __syncthreads();
    int wpos = kvidx[pos0 + b];
#pragma unroll
    for (int r = 0; r < 16; r++) {
        int cl = r * 4 + a;
        Vbt[(size_t)(c0 + cl) * S_LEN + wpos] = T[b][cl];
    }
}

// ---------------- flash attention v7: 32x32 MFMA, no atomics, 2-ahead pipeline ----
// 384 blocks of 256 threads: (head, q-block of 128 rows) — NO chunking.
// Round-4 evidence: per-tile wall ~10k cyc invariant across structures, and
// WRITE_SIZE 162MB == 40M device-scope fp32 atomicAdds (the chunk combine).
// Those L2 RMWs congest the memory system the prefetches traverse -> the
// vmcnt(0) stall IS the cost. v7: (a) every block owns its rows -> direct bf16
// epilogue, zero atomics, no memset/norm; (b) 3-buffer 2-ahead prefetch with
// counted vmcnt(8) (vmcnt(0) only on the last tile) -> latency budget = two
// compute phases; per-wave counted wait + barrier = collective guarantee.
// Compute core / swizzles / fragment layouts byte-identical to the passed v6.
// Heavy q-blocks dispatch first (head-interleaved) for balance.
__global__ __launch_bounds__(256, 1) void attn_kernel(const unsigned short* __restrict__ Qb,
                                                      const unsigned short* __restrict__ Kb,
                                                      const unsigned short* __restrict__ Vbt,
                                                      unsigned short* __restrict__ attn_out) {
    __shared__ __align__(16) unsigned short Kl[3][32 * 256];   // 3 x 16 KB, keys x dims (chunk-swizzled)
    __shared__ __align__(16) unsigned short Vl[3][256 * 32];   // 3 x 16 KB, dims x keys (chunk-swizzled)
    __shared__ __align__(16) unsigned short Plb[4][1024];      // per-wave P [32 q][32 k], swizzled

    // decode: head-interleaved, heavy q-blocks first
    const int h = blockIdx.x & 15;
    const int qb = 23 - (blockIdx.x >> 4);

    const int kv = h >> 1;
    const int q0 = qb * 128;
    const int tid = threadIdx.x;
    const int wid = tid >> 6, lane = tid & 63;
    const int ln32 = lane & 31, hi = lane >> 5;
    const int qw0 = q0 + wid * 32;              // this wave's 32 q-rows

    // Q fragments: A-operand row = lane&31, k = (lane>>5)*8 + j per 16-chunk
    bf16x8 qf[16];
    {
        const unsigned short* qrow = Qb + ((size_t)h * S_LEN + qw0 + ln32) * HDIM + hi * 8;
#pragma unroll
        for (int s = 0; s < 16; s++)
            qf[s] = *(const bf16x8*)(qrow + s * 16);
    }

    f32x16 pacc[8];
#pragma unroll
    for (int dt = 0; dt < 8; dt++) {
#pragma unroll
        for (int i = 0; i < 16; i++) pacc[dt][i] = 0.f;
    }
    float ps[16];
#pragma unroll
    for (int r = 0; r < 16; r++) ps[r] = 0.f;

    const int imin = qw0;
    const int imax = qw0 + 31;

    const int t_lo = (q0 >= WIN) ? ((q0 - (WIN - 1)) >> 5) : 0;
    const int t_hi = (q0 + 127) >> 5;
    const int ts = t_lo;
    const int te = t_hi + 1;                    // tn = te-ts >= 4 always

    // ---- DMA staging source pointers (pre-swizzled; verified in v6) ----
    const unsigned short* kSrcA = Kb + ((size_t)kv * S_LEN + (tid >> 5)) * HDIM
                                  + ((tid & 31) ^ ((tid >> 5) & 7)) * 8;
    const unsigned short* vSrcA = Vbt + ((size_t)kv * HDIM + (tid >> 2)) * S_LEN
                                  + ((tid & 3) ^ ((tid >> 3) & 3)) * 8;

    auto STAGE = [&](int tile, int b) {
        const int p0x = tile * 32;
        const unsigned short* ksg = kSrcA + (size_t)p0x * HDIM;
        const unsigned short* vsg = vSrcA + p0x;
#pragma unroll
        for (int c = 0; c < 4; c++)
            async16(ksg + (size_t)(c * 8) * HDIM, &Kl[b][(c * 256 + tid) * 8]);
#pragma unroll
        for (int c = 0; c < 4; c++)
            async16(vsg + (size_t)(c * 64) * S_LEN, &Vl[b][(c * 256 + tid) * 8]);
    };

    // prologue: stage first two tiles (tn >= 4 guarantees both exist)
    STAGE(ts, 0);
    STAGE(ts + 1, 1);

    unsigned short* plw = &Plb[wid][0];
    const int kswz = ln32 & 7;
    int rb = 0;                                 // read-buffer index

    for (int tt = ts; tt < te; tt++) {
        // counted wait: oldest 8 (this tile's chunks) done; next tile's 8 may fly.
        // FIFO vmcnt semantics (m135): drains oldest-first. Per-wave wait +
        // barrier => all 4 waves' portions of tile tt are in LDS.
        if (tt + 1 < te) { asm volatile("s_waitcnt vmcnt(8)" ::: "memory"); }
        else             { asm volatile("s_waitcnt vmcnt(0)" ::: "memory"); }
        __builtin_amdgcn_s_barrier();
        asm volatile("" ::: "memory");

        // 2-ahead prefetch into the buffer last read at iter tt-1 (all waves
        // passed the barrier above after finishing that read -> safe).
        if (tt + 2 < te) {
            const int wb = (rb >= 1) ? rb - 1 : 2;   // (rb+2)%3
            STAGE(tt + 2, wb);
        }

        const int p0 = tt * 32;
        const bool live = (p0 <= imax) && (p0 + 31 >= imin - WIN + 1);
        if (live) {
            // QK^T: S[32q][32k]; A=Q (regs), B=K from LDS.
            const unsigned short* kb = Kl[rb];
            f32x16 sacc;
#pragma unroll
            for (int i = 0; i < 16; i++) sacc[i] = 0.f;
#pragma unroll
            for (int s = 0; s < 16; s++) {
                bf16x8 kf = *(const bf16x8*)(kb + ln32 * 256 + ((((s << 1) + hi) ^ kswz) << 3));
                sacc = __builtin_amdgcn_mfma_f32_32x32x16_bf16(qf[s], kf, sacc, 0, 0, 0);
            }

            const bool full = (p0 + 31 <= imin) && (p0 >= imax - WIN + 1);
#pragma unroll
            for (int r = 0; r < 16; r++) {
                float z = __expf(sacc[r] * 0.04f);
                float t = fmaf(-100.f, __builtin_amdgcn_rcpf(z + 1.f), 50.f);
                float p = __expf(t);
                const int qloc = (r & 3) + 8 * (r >> 2) + 4 * hi;
                if (!full) {
                    const int i = qw0 + qloc;
                    const int j = p0 + ln32;
                    p = ((j <= i) && (j + WIN > i)) ? p : 0.f;
                }
                ps[r] += p;
                plw[qloc * 32 + (((ln32 >> 3) ^ ((qloc >> 1) & 3)) << 3) + (ln32 & 7)] = f2bf(p);
            }

            // PV: out[32q][256d]; A=P (row=q=lane&31, k=keys), B=V [d][key]
            bf16x8 pa0 = *(const bf16x8*)(plw + ln32 * 32 + ((hi ^ ((ln32 >> 1) & 3)) << 3));
            bf16x8 pa1 = *(const bf16x8*)(plw + ln32 * 32 + (((2 + hi) ^ ((ln32 >> 1) & 3)) << 3));
            const unsigned short* vb = Vl[rb];
#pragma unroll
            for (int dt = 0; dt < 8; dt++) {
                const int d = dt * 32 + ln32;
                const int vswz = (d >> 1) & 3;
                bf16x8 v0 = *(const bf16x8*)(vb + d * 32 + ((hi ^ vswz) << 3));
                pacc[dt] = __builtin_amdgcn_mfma_f32_32x32x16_bf16(pa0, v0, pacc[dt], 0, 0, 0);
                bf16x8 v1 = *(const bf16x8*)(vb + d * 32 + (((2 + hi) ^ vswz) << 3));
                pacc[dt] = __builtin_amdgcn_mfma_f32_32x32x16_bf16(pa1, v1, pacc[dt], 0, 0, 0);
            }
        }
        rb = (rb >= 2) ? 0 : rb + 1;
    }

    // reduce ps over the 32 lanes of each half-wave (keys axis)
#pragma unroll
    for (int r = 0; r < 16; r++) {
        float s = ps[r];
#pragma unroll
        for (int o = 1; o <= 16; o <<= 1)
            s += __shfl_xor(s, o);
        ps[r] = s;
    }

    // direct bf16 epilogue (no partials anywhere)
#pragma unroll
    for (int dt = 0; dt < 8; dt++) {
#pragma unroll
        for (int r = 0; r < 16; r++) {
            const int q = qw0 + (r & 3) + 8 * (r >> 2) + 4 * hi;
            float o = pacc[dt][r] * __builtin_amdgcn_rcpf(ps[r]);
            attn_out[(size_t)q * 4096 + h * HDIM + dt * 32 + ln32] = f2bf(o);
        }
    }
}

// ---------------- launch ----------------
extern "C" void kernel_launch(void* const* d_in, const int* in_sizes, int n_in,
                              void* d_out, int out_size, void* d_ws, size_t ws_size,
                              hipStream_t stream) {
    (void)in_sizes; (void)n_in; (void)out_size; (void)ws_size;
    const float* hidden = (const float*)d_in[0];
    const float* freqs  = (const float*)d_in[1];
    const int* kvidx    = (const int*)d_in[2];
    const float* qkv_w  = (const float*)d_in[6];
    const float* o_w    = (const float*)d_in[7];
    float* out = (float*)d_out;

    char* ws = (char*)d_ws;
    unsigned short* hs_bf   = (unsigned short*)(ws);                 // 22.0 MB
    unsigned short* w1_bf   = (unsigned short*)(ws + 22020096);
    unsigned short* w2_bf   = (unsigned short*)(ws + 80740352);
    unsigned short* qkv_bf  = (unsigned short*)(ws + 110100480);     // 50.3 MB
    unsigned short* Qb      = (unsigned short*)(ws + 160432128);
    unsigned short* Kb      = (unsigned short*)(ws + 185597952);
    unsigned short* Vbt     = (unsigned short*)(ws + 198180864);
    unsigned short* attn_bf = (unsigned short*)(ws + 210763776);

    cast_bf16_kernel<<<10752, 256, 0, stream>>>(hidden, hs_bf, 11010048);
    cast_bf16_kernel<<<28672, 256, 0, stream>>>(qkv_w, w1_bf, 29360128);
    cast_bf16_kernel<<<14336, 256, 0, stream>>>(o_w, w2_bf, 14680064);

    gemm_bt<1><<<dim3(64, 24), 256, 0, stream>>>(hs_bf, w1_bf, (void*)qkv_bf, 8192, 3584);

    rope_kernel<<<36864, 256, 0, stream>>>(qkv_bf, freqs, kvidx, Qb, Kb);
    vtrans_kernel<<<dim3(48, 32), 256, 0, stream>>>(qkv_bf, kvidx, Vbt);

    attn_kernel<<<384, 256, 0, stream>>>(Qb, Kb, Vbt, attn_bf);

    gemm_bt<0><<<dim3(28, 24), 256, 0, stream>>>(attn_bf, w2_bf, (void*)out, 3584, 4096);
}

// Round 6
// 874.403 us; speedup vs baseline: 1.1598x; 1.0342x over previous
//
#include <hip/hip_runtime.h>

#define S_LEN 3072
#define NHQ 16
#define NKVH 8
#define HDIM 256
#define WIN 2048
#define QKV_COLS 8192

typedef __bf16 bf16x8 __attribute__((ext_vector_type(8)));
typedef float f32x4 __attribute__((ext_vector_type(4)));
typedef float f32x16 __attribute__((ext_vector_type(16)));

__device__ __forceinline__ unsigned short f2bf(float f) {
    union { float f; unsigned u; } v; v.f = f;
    unsigned r = v.u + 0x7FFFu + ((v.u >> 16) & 1u);
    return (unsigned short)(r >> 16);
}
__device__ __forceinline__ float bf2f(unsigned short u) {
    union { unsigned u; float f; } v; v.u = ((unsigned)u) << 16; return v.f;
}

typedef __attribute__((address_space(3))) void lds_void_t;
typedef const __attribute__((address_space(1))) void glb_void_t;
__device__ __forceinline__ void async16(const void* g, void* l) {
    __builtin_amdgcn_global_load_lds((glb_void_t*)g, (lds_void_t*)l, 16, 0, 0);
}

// ---------------- fp32 -> bf16 cast ----------------
__global__ __launch_bounds__(256) void cast_bf16_kernel(const float* __restrict__ src,
                                                        unsigned short* __restrict__ dst,
                                                        int n) {
    int i = (blockIdx.x * 256 + threadIdx.x) * 4;
    if (i >= n) return;
    float4 v = *(const float4*)(src + i);
    ushort4 o;
    o.x = f2bf(v.x); o.y = f2bf(v.y); o.z = f2bf(v.z); o.w = f2bf(v.w);
    *(ushort4*)(dst + i) = o;
}

// ---------------- bf16 GEMM: C[M,N] = A[M,K] @ B[N,K]^T ----------------
// v8: attn-v7 pipeline transplanted — 3-buffer LDS, 2-ahead STAGE, counted
// vmcnt(4) (drain-0 only on the final K-step), ONE raw s_barrier per K-step
// (vs two __syncthreads + full vmcnt drain). Buffer written by STAGE at iter t
// was last read at iter t-1; every wave passed barrier t after those reads ->
// safe (same argument verified in attn v7). Per-wave counted wait + barrier
// => whole tile visible. XCD-aware bijective block swizzle (T1) kept.
template <int OUT_BF16>
__global__ __launch_bounds__(256) void gemm_bt(const unsigned short* __restrict__ A,
                                               const unsigned short* __restrict__ B,
                                               void* __restrict__ Cv,
                                               int N, int K) {
    __shared__ __align__(16) unsigned short At[3][128 * 32];
    __shared__ __align__(16) unsigned short Bt[3][128 * 32];
    const int tid = threadIdx.x;
    const int wid = tid >> 6, lane = tid & 63;
    const int ln = lane & 15, quad = lane >> 4;

    int bm, bn;
    {
        const int nwg = gridDim.x * gridDim.y;
        int orig = blockIdx.y * gridDim.x + blockIdx.x;
        int wg = orig;
        if ((nwg & 7) == 0) {
            const int cpx = nwg >> 3;
            wg = (orig & 7) * cpx + (orig >> 3);
        }
        bm = wg / gridDim.x;
        bn = wg % gridDim.x;
    }
    const int wm = wid >> 1, wn = wid & 1;

    const f32x4 fzero = {0.f, 0.f, 0.f, 0.f};
    f32x4 acc[4][4];
#pragma unroll
    for (int i = 0; i < 4; i++) {
#pragma unroll
        for (int j = 0; j < 4; j++) acc[i][j] = fzero;
    }

    const unsigned short* gA = A + (size_t)(bm * 128 + wid * 32 + (lane >> 2)) * K + (lane & 3) * 8;
    const unsigned short* gB = B + (size_t)(bn * 128 + wid * 32 + (lane >> 2)) * K + (lane & 3) * 8;
    const int lbase = wid * 32 * 32;   // wave-uniform LDS base (HW adds lane*16B)

    auto STAGE = [&](int k0, int b) {
        async16(gA + k0,          &At[b][lbase]);
        async16(gA + k0 + 16 * K, &At[b][lbase + 16 * 32]);
        async16(gB + k0,          &Bt[b][lbase]);
        async16(gB + k0 + 16 * K, &Bt[b][lbase + 16 * 32]);
    };

    const int NT = K >> 5;             // K/32 steps (>= 3 for all launches)
    STAGE(0, 0);
    STAGE(32, 1);
    int rb = 0;

    for (int t = 0; t < NT; ++t) {
        // counted wait: this tile's 4 DMAs done (FIFO); next tile's 4 may fly.
        if (t + 1 < NT) { asm volatile("s_waitcnt vmcnt(4)" ::: "memory"); }
        else            { asm volatile("s_waitcnt vmcnt(0)" ::: "memory"); }
        __builtin_amdgcn_s_barrier();
        asm volatile("" ::: "memory");

        // 2-ahead prefetch into the buffer last read at iter t-1 (all waves
        // passed the barrier above after finishing that read -> safe).
        if (t + 2 < NT) {
            const int wb = (rb >= 1) ? rb - 1 : 2;   // (rb+2)%3
            STAGE((t + 2) * 32, wb);
        }

        bf16x8 af[4], bfr[4];
#pragma unroll
        for (int mt = 0; mt < 4; mt++)
            af[mt] = *(const bf16x8*)(&At[rb][(wm * 64 + mt * 16 + ln) * 32 + quad * 8]);
#pragma unroll
        for (int nt = 0; nt < 4; nt++)
            bfr[nt] = *(const bf16x8*)(&Bt[rb][(wn * 64 + nt * 16 + ln) * 32 + quad * 8]);
#pragma unroll
        for (int mt = 0; mt < 4; mt++) {
#pragma unroll
            for (int nt = 0; nt < 4; nt++)
                acc[mt][nt] = __builtin_amdgcn_mfma_f32_16x16x32_bf16(af[mt], bfr[nt], acc[mt][nt], 0, 0, 0);
        }
        rb = (rb >= 2) ? 0 : rb + 1;
    }

    const int row0 = bm * 128 + wm * 64 + quad * 4;
    const int col0 = bn * 128 + wn * 64 + ln;
    if (OUT_BF16) {
        unsigned short* C = (unsigned short*)Cv;
#pragma unroll
        for (int mt = 0; mt < 4; mt++) {
#pragma unroll
            for (int nt = 0; nt < 4; nt++) {
#pragma unroll
                for (int rr = 0; rr < 4; rr++)
                    C[(size_t)(row0 + mt * 16 + rr) * N + col0 + nt * 16] = f2bf(acc[mt][nt][rr]);
            }
        }
    } else {
        float* C = (float*)Cv;
#pragma unroll
        for (int mt = 0; mt < 4; mt++) {
#pragma unroll
            for (int nt = 0; nt < 4; nt++) {
#pragma unroll
                for (int rr = 0; rr < 4; rr++)
                    C[(size_t)(row0 + mt * 16 + rr) * N + col0 + nt * 16] = acc[mt][nt][rr];
            }
        }
    }
}

// ---------------- RoPE for Q (scaled) and K ----------------
__global__ __launch_bounds__(256) void rope_kernel(const unsigned short* __restrict__ qkv,
                                                   const float* __restrict__ freqs,
                                                   const int* __restrict__ kvidx,
                                                   unsigned short* __restrict__ Qb,
                                                   unsigned short* __restrict__ Kb) {
    int t = blockIdx.x * 256 + threadIdx.x;
    int d = t & 127;
    int t2 = t >> 7;
    int hh = t2 % 24;
    int pos = t2 / 24;
    if (pos >= S_LEN) return;
    float2 cs = *(const float2*)(freqs + ((size_t)pos * 128 + d) * 2);
    if (hh < NHQ) {
        const unsigned short* src = qkv + (size_t)pos * QKV_COLS + hh * HDIM + d;
        float x1 = bf2f(src[0]), x2 = bf2f(src[128]);
        float o1 = (x1 * cs.x - x2 * cs.y) * 0.0625f;
        float o2 = (x1 * cs.y + x2 * cs.x) * 0.0625f;
        unsigned short* dst = Qb + ((size_t)hh * S_LEN + pos) * HDIM + d;
        dst[0] = f2bf(o1);
        dst[128] = f2bf(o2);
    } else {
        int kvh = hh - NHQ;
        const unsigned short* src = qkv + (size_t)pos * QKV_COLS + NHQ * HDIM + kvh * HDIM + d;
        float x1 = bf2f(src[0]), x2 = bf2f(src[128]);
        float o1 = x1 * cs.x - x2 * cs.y;
        float o2 = x1 * cs.y + x2 * cs.x;
        int wpos = kvidx[pos];
        unsigned short* dst = Kb + ((size_t)kvh * S_LEN + wpos) * HDIM + d;
        dst[0] = f2bf(o1);
        dst[128] = f2bf(o2);
    }
}

// ---------------- V transpose ----------------
__global__ __launch_bounds__(256) void vtrans_kernel(const unsigned short* __restrict__ qkv,
                                                     const int* __restrict__ kvidx,
                                                     unsigned short* __restrict__ Vbt) {
    __shared__ unsigned short T[64][72];
    int pos0 = blockIdx.x * 64;
    int c0 = blockIdx.y * 64;
    int a = threadIdx.x >> 6;
    int b = threadIdx.x & 63;
#pragma unroll
    for (int r = 0; r < 16; r++) {
        int pl = r * 4 + a;
        T[pl][b] = qkv[(size_t)(pos0 + pl) * QKV_COLS + 6144 + c0 + b];
    }
    __syncthreads();
    int wpos = kvidx[pos0 + b];
#pragma unroll
    for (int r = 0; r < 16; r++) {
        int cl = r * 4 + a;
        Vbt[(size_t)(c0 + cl) * S_LEN + wpos] = T[b][cl];
    }
}

// ---------------- flash attention v7: 32x32 MFMA, no atomics, 2-ahead pipeline ----
// (passed round 5: 384 blocks, direct bf16 epilogue, counted vmcnt) — unchanged.
__global__ __launch_bounds__(256, 1) void attn_kernel(const unsigned short* __restrict__ Qb,
                                                      const unsigned short* __restrict__ Kb,
                                                      const unsigned short* __restrict__ Vbt,
                                                      unsigned short* __restrict__ attn_out) {
    __shared__ __align__(16) unsigned short Kl[3][32 * 256];
    __shared__ __align__(16) unsigned short Vl[3][256 * 32];
    __shared__ __align__(16) unsigned short Plb[4][1024];

    const int h = blockIdx.x & 15;
    const int qb = 23 - (blockIdx.x >> 4);

    const int kv = h >> 1;
    const int q0 = qb * 128;
    const int tid = threadIdx.x;
    const int wid = tid >> 6, lane = tid & 63;
    const int ln32 = lane & 31, hi = lane >> 5;
    const int qw0 = q0 + wid * 32;

    bf16x8 qf[16];
    {
        const unsigned short* qrow = Qb + ((size_t)h * S_LEN + qw0 + ln32) * HDIM + hi * 8;
#pragma unroll
        for (int s = 0; s < 16; s++)
            qf[s] = *(const bf16x8*)(qrow + s * 16);
    }

    f32x16 pacc[8];
#pragma unroll
    for (int dt = 0; dt < 8; dt++) {
#pragma unroll
        for (int i = 0; i < 16; i++) pacc[dt][i] = 0.f;
    }
    float ps[16];
#pragma unroll
    for (int r = 0; r < 16; r++) ps[r] = 0.f;

    const int imin = qw0;
    const int imax = qw0 + 31;

    const int t_lo = (q0 >= WIN) ? ((q0 - (WIN - 1)) >> 5) : 0;
    const int t_hi = (q0 + 127) >> 5;
    const int ts = t_lo;
    const int te = t_hi + 1;

    const unsigned short* kSrcA = Kb + ((size_t)kv * S_LEN + (tid >> 5)) * HDIM
                                  + ((tid & 31) ^ ((tid >> 5) & 7)) * 8;
    const unsigned short* vSrcA = Vbt + ((size_t)kv * HDIM + (tid >> 2)) * S_LEN
                                  + ((tid & 3) ^ ((tid >> 3) & 3)) * 8;

    auto STAGE = [&](int tile, int b) {
        const int p0x = tile * 32;
        const unsigned short* ksg = kSrcA + (size_t)p0x * HDIM;
        const unsigned short* vsg = vSrcA + p0x;
#pragma unroll
        for (int c = 0; c < 4; c++)
            async16(ksg + (size_t)(c * 8) * HDIM, &Kl[b][(c * 256 + tid) * 8]);
#pragma unroll
        for (int c = 0; c < 4; c++)
            async16(vsg + (size_t)(c * 64) * S_LEN, &Vl[b][(c * 256 + tid) * 8]);
    };

    STAGE(ts, 0);
    STAGE(ts + 1, 1);

    unsigned short* plw = &Plb[wid][0];
    const int kswz = ln32 & 7;
    int rb = 0;

    for (int tt = ts; tt < te; tt++) {
        if (tt + 1 < te) { asm volatile("s_waitcnt vmcnt(8)" ::: "memory"); }
        else             { asm volatile("s_waitcnt vmcnt(0)" ::: "memory"); }
        __builtin_amdgcn_s_barrier();
        asm volatile("" ::: "memory");

        if (tt + 2 < te) {
            const int wb = (rb >= 1) ? rb - 1 : 2;
            STAGE(tt + 2, wb);
        }

        const int p0 = tt * 32;
        const bool live = (p0 <= imax) && (p0 + 31 >= imin - WIN + 1);
        if (live) {
            const unsigned short* kb = Kl[rb];
            f32x16 sacc;
#pragma unroll
            for (int i = 0; i < 16; i++) sacc[i] = 0.f;
#pragma unroll
            for (int s = 0; s < 16; s++) {
                bf16x8 kf = *(const bf16x8*)(kb + ln32 * 256 + ((((s << 1) + hi) ^ kswz) << 3));
                sacc = __builtin_amdgcn_mfma_f32_32x32x16_bf16(qf[s], kf, sacc, 0, 0, 0);
            }

            const bool full = (p0 + 31 <= imin) && (p0 >= imax - WIN + 1);
#pragma unroll
            for (int r = 0; r < 16; r++) {
                float z = __expf(sacc[r] * 0.04f);
                float t = fmaf(-100.f, __builtin_amdgcn_rcpf(z + 1.f), 50.f);
                float p = __expf(t);
                const int qloc = (r & 3) + 8 * (r >> 2) + 4 * hi;
                if (!full) {
                    const int i = qw0 + qloc;
                    const int j = p0 + ln32;
                    p = ((j <= i) && (j + WIN > i)) ? p : 0.f;
                }
                ps[r] += p;
                plw[qloc * 32 + (((ln32 >> 3) ^ ((qloc >> 1) & 3)) << 3) + (ln32 & 7)] = f2bf(p);
            }

            bf16x8 pa0 = *(const bf16x8*)(plw + ln32 * 32 + ((hi ^ ((ln32 >> 1) & 3)) << 3));
            bf16x8 pa1 = *(const bf16x8*)(plw + ln32 * 32 + (((2 + hi) ^ ((ln32 >> 1) & 3)) << 3));
            const unsigned short* vb = Vl[rb];
#pragma unroll
            for (int dt = 0; dt < 8; dt++) {
                const int d = dt * 32 + ln32;
                const int vswz = (d >> 1) & 3;
                bf16x8 v0 = *(const bf16x8*)(vb + d * 32 + ((hi ^ vswz) << 3));
                pacc[dt] = __builtin_amdgcn_mfma_f32_32x32x16_bf16(pa0, v0, pacc[dt], 0, 0, 0);
                bf16x8 v1 = *(const bf16x8*)(vb + d * 32 + (((2 + hi) ^ vswz) << 3));
                pacc[dt] = __builtin_amdgcn_mfma_f32_32x32x16_bf16(pa1, v1, pacc[dt], 0, 0, 0);
            }
        }
        rb = (rb >= 2) ? 0 : rb + 1;
    }

#pragma unroll
    for (int r = 0; r < 16; r++) {
        float s = ps[r];
#pragma unroll
        for (int o = 1; o <= 16; o <<= 1)
            s += __shfl_xor(s, o);
        ps[r] = s;
    }

#pragma unroll
    for (int dt = 0; dt < 8; dt++) {
#pragma unroll
        for (int r = 0; r < 16; r++) {
            const int q = qw0 + (r & 3) + 8 * (r >> 2) + 4 * hi;
            float o = pacc[dt][r] * __builtin_amdgcn_rcpf(ps[r]);
            attn_out[(size_t)q * 4096 + h * HDIM + dt * 32 + ln32] = f2bf(o);
        }
    }
}

// ---------------- launch ----------------
extern "C" void kernel_launch(void* const* d_in, const int* in_sizes, int n_in,
                              void* d_out, int out_size, void* d_ws, size_t ws_size,
                              hipStream_t stream) {
    (void)in_sizes; (void)n_in; (void)out_size; (void)ws_size;
    const float* hidden = (const float*)d_in[0];
    const float* freqs  = (const float*)d_in[1];
    const int* kvidx    = (const int*)d_in[2];
    const float* qkv_w  = (const float*)d_in[6];
    const float* o_w    = (const float*)d_in[7];
    float* out = (float*)d_out;

    char* ws = (char*)d_ws;
    unsigned short* hs_bf   = (unsigned short*)(ws);                 // 22.0 MB
    unsigned short* w1_bf   = (unsigned short*)(ws + 22020096);
    unsigned short* w2_bf   = (unsigned short*)(ws + 80740352);
    unsigned short* qkv_bf  = (unsigned short*)(ws + 110100480);     // 50.3 MB
    unsigned short* Qb      = (unsigned short*)(ws + 160432128);
    unsigned short* Kb      = (unsigned short*)(ws + 185597952);
    unsigned short* Vbt     = (unsigned short*)(ws + 198180864);
    unsigned short* attn_bf = (unsigned short*)(ws + 210763776);

    cast_bf16_kernel<<<10752, 256, 0, stream>>>(hidden, hs_bf, 11010048);
    cast_bf16_kernel<<<28672, 256, 0, stream>>>(qkv_w, w1_bf, 29360128);
    cast_bf16_kernel<<<14336, 256, 0, stream>>>(o_w, w2_bf, 14680064);

    gemm_bt<1><<<dim3(64, 24), 256, 0, stream>>>(hs_bf, w1_bf, (void*)qkv_bf, 8192, 3584);

    rope_kernel<<<36864, 256, 0, stream>>>(qkv_bf, freqs, kvidx, Qb, Kb);
    vtrans_kernel<<<dim3(48, 32), 256, 0, stream>>>(qkv_bf, kvidx, Vbt);

    attn_kernel<<<384, 256, 0, stream>>>(Qb, Kb, Vbt, attn_bf);

    gemm_bt<0><<<dim3(28, 24), 256, 0, stream>>>(attn_bf, w2_bf, (void*)out, 3584, 4096);
}